// Round 3
// baseline (361.207 us; speedup 1.0000x reference)
//
#include <hip/hip_runtime.h>
#include <stdint.h>

// ---------------------------------------------------------------------------
// LocalAtomAttention v2 on gfx950 — fully MFMA attention, register-resident.
//   x:[16,4096,4,128] f32, mask:[16,4096,4] int, Wq/bq/Wk/bk/Wv/bv/Wo/bo.
// Design:
//   - wconv pre-pass: W* -> f16 in d_ws (L2-resident)
//   - 4096 blocks x 256 thr; wave w = head w; 16 residues (64 atom rows)/block
//   - Q^T,K^T via mfma(A=W, B=x^T-frag); V via mfma(A=x^T-frag, B=W)
//     (A- and B-frag layouts coincide, so the SAME x registers serve both)
//   - scores: S^T = mfma(ktf, qtf) with the shared implicit d-permutation;
//     softmax is lane-local (4 scores/lane, mask-gated, off-diag lanes zeroed)
//   - PV: O^T = mfma_16x16x16(A=V-frag, B=P^T-frag) -> consecutive-channel
//     register quads -> b64 LDS writes into sO (the ONLY LDS buffer, 17 KB)
//   - one barrier; out-proj reads sO as natural A-frags (b128, padded stride)
// ---------------------------------------------------------------------------

typedef __fp16 f16;   // storage-only; builtins want __fp16 ext-vectors
typedef f16   f16x2 __attribute__((ext_vector_type(2)));
typedef f16   f16x4 __attribute__((ext_vector_type(4)));
typedef f16   f16x8 __attribute__((ext_vector_type(8)));
typedef float f32x4 __attribute__((ext_vector_type(4)));

#define N_RES 65536   // B*L = 16*4096
#define RPB   16      // residues per block
#define MROWS 64      // RPB*4 atom rows
#define CDIM  128
#define SOP   136     // padded u16 row stride for sO (272 B: breaks bank aliasing)

// pack two f32 -> one dword of two f16 (v_cvt_pkrtz, 1 instruction)
__device__ __forceinline__ uint32_t pkh(float a, float b) {
    f16x2 h = __builtin_amdgcn_cvt_pkrtz(a, b);
    return __builtin_bit_cast(uint32_t, h);
}

// --------------------------- W fp32 -> f16 pre-pass -------------------------
__global__ void wconv_kernel(const float* __restrict__ wq, const float* __restrict__ wk,
                             const float* __restrict__ wv, const float* __restrict__ wo,
                             uint16_t* __restrict__ dst) {
    int i = blockIdx.x * 256 + threadIdx.x;          // 65536 threads total
    const float* s = (i < 16384) ? wq : (i < 32768) ? wk : (i < 49152) ? wv : wo;
    f16 h = (f16)s[i & 16383];                       // v_cvt_f16_f32 (RNE)
    dst[i] = __builtin_bit_cast(uint16_t, h);
}

// load one 16-byte W fragment: row-major [outch][cin], 8 f16 at (row, col..col+7)
template <bool USEWS>
__device__ __forceinline__ f16x8 ldw16(const uint16_t* __restrict__ wbf,
                                       const float* __restrict__ w32,
                                       int goff, int row, int col) {
    if constexpr (USEWS) {
        return *(const f16x8*)(wbf + goff + row * CDIM + col);
    } else {
        const float4* p = (const float4*)(w32 + row * CDIM + col);
        float4 a = p[0], b = p[1];
        uint4 u = make_uint4(pkh(a.x, a.y), pkh(a.z, a.w), pkh(b.x, b.y), pkh(b.z, b.w));
        return __builtin_bit_cast(f16x8, u);
    }
}

// --------------------------------- main -------------------------------------
template <bool USEWS>
__global__ __launch_bounds__(256, 3)
void laa_main(const float* __restrict__ x, const int* __restrict__ mask,
              const float* __restrict__ Wq, const float* __restrict__ bq,
              const float* __restrict__ Wk, const float* __restrict__ bk,
              const float* __restrict__ Wv, const float* __restrict__ bv,
              const float* __restrict__ Wo, const float* __restrict__ bo,
              const uint16_t* __restrict__ wbf,
              float* __restrict__ out) {
    __shared__ uint16_t sO[MROWS * SOP];   // 17408 B — only LDS buffer

    const int tid  = threadIdx.x;
    const int wave = tid >> 6;        // head index; owns channels [hb, hb+32)
    const int lane = tid & 63;
    const int l15  = lane & 15;
    const int quad = lane >> 4;
    const int hb   = wave * 32;
    const long m0  = (long)blockIdx.x * MROWS;

    const f32x4 vzero = {0.f, 0.f, 0.f, 0.f};

    // ---- fused Q^T / K^T / V projection, all register-resident -------------
    // QT/KT C-layout: [outch = nd*16 + 4*quad + r, atom = l15] per row-group m
    // V    C-layout: [atom  = 4*quad + r, outch = nt*16 + l15] per row-group m
    f32x4 qt[4][2], kt[4][2], vv[4][2];
    #pragma unroll
    for (int m = 0; m < 4; ++m)
        #pragma unroll
        for (int n = 0; n < 2; ++n) { qt[m][n] = vzero; kt[m][n] = vzero; vv[m][n] = vzero; }

    #pragma unroll
    for (int ks = 0; ks < 4; ++ks) {
        // x^T-fragment: lane holds atom = l15 (within group m), cin = ks*32+quad*8+j
        f16x8 xf[4];
        #pragma unroll
        for (int m = 0; m < 4; ++m) {
            const float4* p = (const float4*)(x + (m0 + m * 16 + l15) * CDIM + ks * 32 + quad * 8);
            float4 a = p[0], b = p[1];
            uint4 u = make_uint4(pkh(a.x, a.y), pkh(a.z, a.w), pkh(b.x, b.y), pkh(b.z, b.w));
            xf[m] = __builtin_bit_cast(f16x8, u);
        }
        f16x8 wqf[2], wkf[2], wvf[2];
        #pragma unroll
        for (int nt = 0; nt < 2; ++nt) {
            int row = hb + nt * 16 + l15, col = ks * 32 + quad * 8;
            wqf[nt] = ldw16<USEWS>(wbf, Wq, 0,     row, col);
            wkf[nt] = ldw16<USEWS>(wbf, Wk, 16384, row, col);
            wvf[nt] = ldw16<USEWS>(wbf, Wv, 32768, row, col);
        }
        #pragma unroll
        for (int m = 0; m < 4; ++m) {
            #pragma unroll
            for (int nt = 0; nt < 2; ++nt) {
                qt[m][nt] = __builtin_amdgcn_mfma_f32_16x16x32_f16(wqf[nt], xf[m], qt[m][nt], 0, 0, 0);
                kt[m][nt] = __builtin_amdgcn_mfma_f32_16x16x32_f16(wkf[nt], xf[m], kt[m][nt], 0, 0, 0);
                vv[m][nt] = __builtin_amdgcn_mfma_f32_16x16x32_f16(xf[m], wvf[nt], vv[m][nt], 0, 0, 0);
            }
        }
    }

    // ---- biases (loaded late to keep GEMM-phase live set small) ------------
    const float s = 0.17677669529663689f;   // 1/sqrt(32), folded into Q side
    float bqs[8], bks[8];
    #pragma unroll
    for (int nd = 0; nd < 2; ++nd) {
        float4 q4 = *(const float4*)(bq + hb + nd * 16 + quad * 4);
        float4 k4 = *(const float4*)(bk + hb + nd * 16 + quad * 4);
        bqs[nd * 4 + 0] = q4.x * s; bqs[nd * 4 + 1] = q4.y * s;
        bqs[nd * 4 + 2] = q4.z * s; bqs[nd * 4 + 3] = q4.w * s;
        bks[nd * 4 + 0] = k4.x;     bks[nd * 4 + 1] = k4.y;
        bks[nd * 4 + 2] = k4.z;     bks[nd * 4 + 3] = k4.w;
    }
    const float bvv0 = bv[hb + l15], bvv1 = bv[hb + 16 + l15];

    // ---- attention via MFMA, softmax lane-local ----------------------------
    // scores: S^T = mfma(ktf, qtf); both frags share the implicit d-order
    // sigma(quad,j) = 4*quad + (j&3) + 16*(j>>2), so the contraction is exact.
    float rm[4];                               // residue mask for epilogue
    const bool diag = (quad == (l15 >> 2));    // lane supplies nonzero P here
    #pragma unroll
    for (int m = 0; m < 4; ++m) {
        uint4 uq, uk;
        uq.x = pkh(qt[m][0][0] * s + bqs[0], qt[m][0][1] * s + bqs[1]);
        uq.y = pkh(qt[m][0][2] * s + bqs[2], qt[m][0][3] * s + bqs[3]);
        uq.z = pkh(qt[m][1][0] * s + bqs[4], qt[m][1][1] * s + bqs[5]);
        uq.w = pkh(qt[m][1][2] * s + bqs[6], qt[m][1][3] * s + bqs[7]);
        uk.x = pkh(kt[m][0][0] + bks[0], kt[m][0][1] + bks[1]);
        uk.y = pkh(kt[m][0][2] + bks[2], kt[m][0][3] + bks[3]);
        uk.z = pkh(kt[m][1][0] + bks[4], kt[m][1][1] + bks[5]);
        uk.w = pkh(kt[m][1][2] + bks[6], kt[m][1][3] + bks[7]);
        f16x8 qtf = __builtin_bit_cast(f16x8, uq);
        f16x8 ktf = __builtin_bit_cast(f16x8, uk);
        // lane (quad,l15) -> S[q = l15, katom = 4*quad + r]
        f32x4 st = __builtin_amdgcn_mfma_f32_16x16x32_f16(ktf, qtf, vzero, 0, 0, 0);

        const int4 mk = *(const int4*)(mask + ((long)blockIdx.x * RPB + m * 4 + quad) * 4);
        rm[m] = (mk.x | mk.y | mk.z | mk.w) ? 1.f : 0.f;
        float mx = -3e38f;
        if (mk.x) mx = fmaxf(mx, st[0]);
        if (mk.y) mx = fmaxf(mx, st[1]);
        if (mk.z) mx = fmaxf(mx, st[2]);
        if (mk.w) mx = fmaxf(mx, st[3]);
        float e0 = mk.x ? __expf(st[0] - mx) : 0.f;
        float e1 = mk.y ? __expf(st[1] - mx) : 0.f;
        float e2 = mk.z ? __expf(st[2] - mx) : 0.f;
        float e3 = mk.w ? __expf(st[3] - mx) : 0.f;
        float inv = 1.f / (e0 + e1 + e2 + e3);   // >=1 always (max elem -> e=1)
        uint2 up = make_uint2(diag ? pkh(e0 * inv, e1 * inv) : 0u,
                              diag ? pkh(e2 * inv, e3 * inv) : 0u);
        f16x4 pf = __builtin_bit_cast(f16x4, up);  // P^T-frag: B[k=4q+j, col=q=l15]

        #pragma unroll
        for (int nt = 0; nt < 2; ++nt) {
            float bb = nt ? bvv1 : bvv0;
            uint2 uv = make_uint2(pkh(vv[m][nt][0] + bb, vv[m][nt][1] + bb),
                                  pkh(vv[m][nt][2] + bb, vv[m][nt][3] + bb));
            f16x4 vbf = __builtin_bit_cast(f16x4, uv); // A[row=d=l15, k=katom=4q+j]
            // O^T tile: lane -> [d = nt*16 + 4*quad + r, atom = l15]
            f32x4 ot = __builtin_amdgcn_mfma_f32_16x16x16f16(vbf, pf, vzero, 0, 0, 0);
            // 4 consecutive channels -> one b64 LDS write
            uint2 w2 = make_uint2(pkh(ot[0], ot[1]), pkh(ot[2], ot[3]));
            *(uint2*)(sO + (m * 16 + l15) * SOP + hb + nt * 16 + quad * 4) = w2;
        }
    }
    __syncthreads();   // the ONLY barrier: out-proj mixes heads

    // ---- output projection: out = O @ Wo^T + bo, * residue_mask ------------
    f32x4 acc2[4][2];
    #pragma unroll
    for (int m = 0; m < 4; ++m)
        #pragma unroll
        for (int nt = 0; nt < 2; ++nt) acc2[m][nt] = vzero;

    #pragma unroll
    for (int ks = 0; ks < 4; ++ks) {
        f16x8 a2[4];
        #pragma unroll
        for (int m = 0; m < 4; ++m)   // natural A-frag: [atom=l15, c=ks*32+quad*8+j]
            a2[m] = *(const f16x8*)(sO + (m * 16 + l15) * SOP + ks * 32 + quad * 8);
        f16x8 b2[2];
        #pragma unroll
        for (int nt = 0; nt < 2; ++nt)
            b2[nt] = ldw16<USEWS>(wbf, Wo, 49152, hb + nt * 16 + l15, ks * 32 + quad * 8);
        #pragma unroll
        for (int m = 0; m < 4; ++m)
            #pragma unroll
            for (int nt = 0; nt < 2; ++nt)
                acc2[m][nt] = __builtin_amdgcn_mfma_f32_16x16x32_f16(a2[m], b2[nt], acc2[m][nt], 0, 0, 0);
    }
    {
        const float bo0 = bo[hb + l15], bo1 = bo[hb + 16 + l15];
        #pragma unroll
        for (int m = 0; m < 4; ++m) {
            // rows m*16+quad*4+r (r=0..3) all belong to local residue m*4+quad,
            // whose mask bit was cached in rm[m] by this same lane.
            #pragma unroll
            for (int nt = 0; nt < 2; ++nt) {
                float bb = nt ? bo1 : bo0;
                #pragma unroll
                for (int r = 0; r < 4; ++r) {
                    long row = m0 + m * 16 + quad * 4 + r;
                    out[row * CDIM + hb + nt * 16 + l15] = (acc2[m][nt][r] + bb) * rm[m];
                }
            }
        }
    }
}

// ------------------------------- launcher -----------------------------------
extern "C" void kernel_launch(void* const* d_in, const int* in_sizes, int n_in,
                              void* d_out, int out_size, void* d_ws, size_t ws_size,
                              hipStream_t stream) {
    const float* x    = (const float*)d_in[0];
    const int*   mask = (const int*)d_in[1];
    const float* Wq   = (const float*)d_in[2];
    const float* bq   = (const float*)d_in[3];
    const float* Wk   = (const float*)d_in[4];
    const float* bk   = (const float*)d_in[5];
    const float* Wv   = (const float*)d_in[6];
    const float* bv   = (const float*)d_in[7];
    const float* Wo   = (const float*)d_in[8];
    const float* bo   = (const float*)d_in[9];
    float* out = (float*)d_out;

    const int nblocks = N_RES / RPB;   // 4096
    const bool usews = ws_size >= (size_t)(4 * 16384 * sizeof(uint16_t));
    if (usews) {
        uint16_t* wbf = (uint16_t*)d_ws;
        wconv_kernel<<<256, 256, 0, stream>>>(Wq, Wk, Wv, Wo, wbf);
        laa_main<true><<<nblocks, 256, 0, stream>>>(x, mask, Wq, bq, Wk, bk, Wv, bv,
                                                    Wo, bo, wbf, out);
    } else {
        laa_main<false><<<nblocks, 256, 0, stream>>>(x, mask, Wq, bq, Wk, bk, Wv, bv,
                                                     Wo, bo, nullptr, out);
    }
}